// Round 11
// baseline (261.387 us; speedup 1.0000x reference)
//
#include <hip/hip_runtime.h>
#include <stdint.h>

typedef unsigned short u16;
typedef unsigned int   u32;

#define NG   512
#define NPG  200
#define EPG  6400
#define NN   (NG*NPG)
#define NE_  (NG*EPG)
#define HID  128
#define HS   232          // h1s/Aq LDS row stride in u16 (breaks bank stride)
#define ZP   136          // Zq row stride in u16

__device__ __forceinline__ float bf2f(u16 b){ u32 u = ((u32)b) << 16; return __builtin_bit_cast(float, u); }
__device__ __forceinline__ u16 f2bf(float f){
    u32 u = __builtin_bit_cast(u32, f);
    u = (u + 0x7FFFu + ((u >> 16) & 1u)) >> 16;
    return (u16)u;
}

typedef __attribute__((ext_vector_type(8))) short bf16x8;
typedef __attribute__((ext_vector_type(4))) float f32x4;

// canon arena (fp32): vectors only
enum : int { cW1=0, cb1=128, cb2=256, cba=384, cbb=896, cbc=1920, cbd=2944, cWe=3456, cbe=8576, cEND=8586 };
// WTa arena (bf16 [n][k])
enum : int { T_Wa=0, T_Wb=65536, T_Wc=589824, T_Wd=1638400, T_END=2162688 };

// ---------------------------------------------------------------------------
// K_prep2: LDS-tiled transposes (coalesced read AND write) for W2,Wa..Wd,
// plus canon vector copies. flag derived per block via ballot on W1 bits.
// ---------------------------------------------------------------------------
struct PrepIn { const void* p[14]; };

__global__ __launch_bounds__(256) void k_prep2(PrepIn in, float* __restrict__ canon,
                                               u16* __restrict__ W2T, u16* __restrict__ WTa)
{
    __shared__ u16 tile[64][72];
    __shared__ int sflag;
    const int tid = threadIdx.x;
    if (tid < 64){
        const u16* wb = (const u16*)in.p[0];
        u16 a = wb[tid], b = wb[64 + tid];
        unsigned long long m1 = __ballot((int)((a >> 7) & 0xFF) >= 0x7F);
        unsigned long long m2 = __ballot((int)((b >> 7) & 0xFF) >= 0x7F);
        if (tid == 0) sflag = (__popcll(m1) + __popcll(m2) > 4) ? 1 : 0;
    }
    __syncthreads();
    const int f = sflag;
    const int bid = blockIdx.x;

    if (bid < 532){
        const void* s; u16* dst; int K, N, t, lgn;
        if      (bid < 4)  { t = bid;       s = in.p[2];  dst = W2T;        K = 128;  N = 128;  lgn = 1; }
        else if (bid < 20) { t = bid - 4;   s = in.p[4];  dst = WTa + T_Wa; K = 128;  N = 512;  lgn = 3; }
        else if (bid < 148){ t = bid - 20;  s = in.p[6];  dst = WTa + T_Wb; K = 512;  N = 1024; lgn = 4; }
        else if (bid < 404){ t = bid - 148; s = in.p[8];  dst = WTa + T_Wc; K = 1024; N = 1024; lgn = 4; }
        else               { t = bid - 404; s = in.p[10]; dst = WTa + T_Wd; K = 1024; N = 512;  lgn = 3; }
        const int k0 = (t >> lgn) * 64, n0 = (t & ((1 << lgn) - 1)) * 64;
        #pragma unroll
        for (int i = 0; i < 16; i++){
            int idx = i*256 + tid;
            int kk = idx >> 6, nn = idx & 63;
            int si = (k0 + kk)*N + n0 + nn;
            tile[nn][kk] = f ? f2bf(((const float*)s)[si]) : ((const u16*)s)[si];
        }
        __syncthreads();
        #pragma unroll
        for (int i = 0; i < 16; i++){
            int idx = i*256 + tid;
            int nn = idx >> 6, kk = idx & 63;
            dst[(size_t)(n0 + nn)*K + k0 + kk] = tile[nn][kk];
        }
    } else {
        int i = (bid - 532)*256 + tid;
        if (i < cEND){
            const void* s; int off;
            if      (i < 128) { s = in.p[0];  off = i; }
            else if (i < 256) { s = in.p[1];  off = i - 128; }
            else if (i < 384) { s = in.p[3];  off = i - 256; }
            else if (i < 896) { s = in.p[5];  off = i - 384; }
            else if (i < 1920){ s = in.p[7];  off = i - 896; }
            else if (i < 2944){ s = in.p[9];  off = i - 1920; }
            else if (i < 3456){ s = in.p[11]; off = i - 2944; }
            else if (i < 8576){ s = in.p[12]; off = i - 3456; }
            else              { s = in.p[13]; off = i - 8576; }
            canon[i] = f ? ((const float*)s)[off] : bf2f(((const u16*)s)[off]);
        }
    }
}

// ---------------------------------------------------------------------------
// K_mega v2: ONE block per graph, 512 threads, 67 KB LDS -> 2 blocks/CU.
//  Edges held in REGISTERS (13 u32/thread). h1s streamed in c-halves
//  (rebuilt from tL per quarter/half, cheap VALU). Aq and Zq UNION one
//  29.7KB buffer (Aq dead after GEMM1 of both halves). W2T fragments
//  preloaded once into registers, reused across quarters.
// A-frag: A[m=lr][k=quad*8+j]; B-frag: B[k=quad*8+j][n=lr]; C/D: col=lr,row=quad*4+r
// ---------------------------------------------------------------------------
__global__ __launch_bounds__(512, 4) void k_mega(
    const int* __restrict__ src, const int* __restrict__ dst,
    const float* __restrict__ W1, const float* __restrict__ b1,
    const float* __restrict__ b2, const u16* __restrict__ W2T,
    float* __restrict__ hg)
{
    __shared__ __align__(16) u16 h1sH[64*HS];   // 29,696 B (one c-half)
    __shared__ __align__(16) u16 AqZ[64*HS];    // 29,696 B (Aq, then Zq 64xZP)
    __shared__ int degIn[NPG], degOut[NPG];
    __shared__ float sVal[NPG], sAgg[NPG], iiL[NPG], ioL[NPG], tL[NPG];
    __shared__ float w1L[HID], b1L[HID], b2L[HID], poolL[HID];

    const int g = blockIdx.x, tid = threadIdx.x;
    u32* aq32 = (u32*)AqZ;

    // edge list -> registers (coalesced loads, issued before first barrier)
    u32 epk[13];
    const int ebase = g * EPG;
    #pragma unroll
    for (int i = 0; i < 13; i++){
        int e = i*512 + tid;
        if (e < EPG){
            int s = src[ebase + e] - g*NPG;
            int d = dst[ebase + e] - g*NPG;
            epk[i] = (u32)s | ((u32)d << 16);
        } else epk[i] = 0xFFFFFFFFu;
    }

    if (tid < NPG){ degIn[tid] = 0; degOut[tid] = 0; sAgg[tid] = 0.f; }
    if (tid < HID){ w1L[tid] = W1[tid]; b1L[tid] = b1[tid]; b2L[tid] = b2[tid]; poolL[tid] = 0.f; }
    __syncthreads();

    // P1: degrees
    #pragma unroll
    for (int i = 0; i < 13; i++){
        if (epk[i] != 0xFFFFFFFFu){
            atomicAdd(&degOut[epk[i] & 0xFFFF], 1);
            atomicAdd(&degIn[epk[i] >> 16], 1);
        }
    }
    __syncthreads();

    // P2: scale factors
    if (tid < NPG){
        float ii = rsqrtf(fmaxf((float)degIn[tid], 1.f));
        float io = rsqrtf(fmaxf((float)degOut[tid], 1.f));
        iiL[tid] = ii; ioL[tid] = io;
        sVal[tid] = (float)degIn[tid] * io;    // h0 = in_deg; s = h0*inv_out
    }
    __syncthreads();

    // P3: layer-1 scalar aggregation
    #pragma unroll
    for (int i = 0; i < 13; i++){
        if (epk[i] != 0xFFFFFFFFu)
            atomicAdd(&sAgg[epk[i] >> 16], sVal[epk[i] & 0xFFFF]);
    }
    __syncthreads();
    if (tid < NPG) tL[tid] = sAgg[tid] * iiL[tid];

    const int w = tid >> 6, lane = tid & 63;
    const int lr = lane & 15, quad = lane >> 4;
    const int wm = w >> 1, wn = w & 1;          // GEMM1: c-16 group, vq-32 group
    const int wm2 = w >> 2, wn2 = w & 3;        // GEMM2: vq-32 group, cout-32 group
    const f32x4 fz = {0.f, 0.f, 0.f, 0.f};

    // preload W2T B-fragments once (reused all 4 quarters)
    bf16x8 wb[4][2];
    #pragma unroll
    for (int ks = 0; ks < 4; ks++)
        #pragma unroll
        for (int nt = 0; nt < 2; nt++)
            wb[ks][nt] = *(const bf16x8*)&W2T[(size_t)(wn2*32 + nt*16 + lr)*HID + ks*32 + quad*8];
    __syncthreads();

    for (int q = 0; q < 4; q++){
        // zero Aq
        uint4* a4 = (uint4*)AqZ;
        for (int i = tid; i < 64*HS/8; i += 512) a4[i] = make_uint4(0,0,0,0);
        __syncthreads();
        // scatter counts (quarter filter) from registers
        #pragma unroll
        for (int i = 0; i < 13; i++){
            u32 u = epk[i];
            if (u != 0xFFFFFFFFu){
                int d = u >> 16;
                int qe = (d * 41) >> 11;        // exact d/50 for d in [0,200)
                if (qe == q){
                    int idx = (d - q*50)*HS + (u & 0xFFFF);
                    atomicAdd(&aq32[idx >> 1], 1u << (16*(idx & 1)));
                }
            }
        }
        __syncthreads();
        // counts -> bf16 (small ints: exact)
        for (int i = tid; i < 64*HS/2; i += 512){
            u32 wv = aq32[i];
            if (wv)
                aq32[i] = (u32)f2bf((float)(wv & 0xFFFFu)) | ((u32)f2bf((float)(wv >> 16)) << 16);
        }
        __syncthreads();

        // GEMM1 in c-halves: Z^T(c x vq) = h1s_half @ Aq^T
        f32x4 accZ[2][2];
        #pragma unroll
        for (int h = 0; h < 2; h++){
            // build h1s half: c in [h*64, h*64+64)
            #pragma unroll 4
            for (int i = 0; i < 64*HS/512; i++){    // 29 iters
                int idx = i*512 + tid;
                int cl = idx / HS, v = idx - cl*HS;
                int c = h*64 + cl;
                u16 o = 0;
                if (v < NPG)
                    o = f2bf(fmaxf(fmaf(tL[v], w1L[c], b1L[c]), 0.f) * ioL[v]);
                h1sH[idx] = o;
            }
            __syncthreads();
            accZ[h][0] = fz; accZ[h][1] = fz;
            for (int ks = 0; ks < 7; ks++){
                bf16x8 af = *(const bf16x8*)&h1sH[(wm*16 + lr)*HS + ks*32 + quad*8];
                #pragma unroll
                for (int nt = 0; nt < 2; nt++){
                    bf16x8 bfr = *(const bf16x8*)&AqZ[(wn*32 + nt*16 + lr)*HS + ks*32 + quad*8];
                    accZ[h][nt] = __builtin_amdgcn_mfma_f32_16x16x32_bf16(af, bfr, accZ[h][nt], 0, 0, 0);
                }
            }
            __syncthreads();   // h1sH rebuild (h=0) / Aq reuse as Zq (h=1) safe after this
        }

        // write Zq into AqZ (Aq fully consumed): Zq[vq][c], c = h*64+wm*16+quad*4+r
        u16* Zq = AqZ;
        #pragma unroll
        for (int h = 0; h < 2; h++)
            #pragma unroll
            for (int nt = 0; nt < 2; nt++){
                int vq = wn*32 + nt*16 + lr;
                int c0 = h*64 + wm*16 + quad*4;
                u16 z0 = f2bf(accZ[h][nt][0]), z1 = f2bf(accZ[h][nt][1]);
                u16 z2 = f2bf(accZ[h][nt][2]), z3 = f2bf(accZ[h][nt][3]);
                uint2 pk = { (u32)z0 | ((u32)z1 << 16), (u32)z2 | ((u32)z3 << 16) };
                *(uint2*)&Zq[vq*ZP + c0] = pk;
            }
        __syncthreads();

        // GEMM2: H(vq x cout) = Zq(64x128) @ W2 ; per wave 2mi x 2nt x 4ks
        f32x4 acc2[2][2];
        #pragma unroll
        for (int mi = 0; mi < 2; mi++)
            #pragma unroll
            for (int nt = 0; nt < 2; nt++) acc2[mi][nt] = fz;
        for (int ks = 0; ks < 4; ks++){
            bf16x8 za[2];
            #pragma unroll
            for (int mi = 0; mi < 2; mi++)
                za[mi] = *(const bf16x8*)&Zq[(wm2*32 + mi*16 + lr)*ZP + ks*32 + quad*8];
            #pragma unroll
            for (int mi = 0; mi < 2; mi++)
                #pragma unroll
                for (int nt = 0; nt < 2; nt++)
                    acc2[mi][nt] = __builtin_amdgcn_mfma_f32_16x16x32_bf16(
                        za[mi], wb[ks][nt], acc2[mi][nt], 0, 0, 0);
        }

        // epilogue: h2 = relu(H*invIn + b2); pool
        #pragma unroll
        for (int mi = 0; mi < 2; mi++)
            #pragma unroll
            for (int nt = 0; nt < 2; nt++){
                int cout = wn2*32 + nt*16 + lr;
                float s = 0.f;
                #pragma unroll
                for (int r = 0; r < 4; r++){
                    int vq = wm2*32 + mi*16 + quad*4 + r;
                    if (vq < 50)
                        s += fmaxf(fmaf(acc2[mi][nt][r], iiL[q*50 + vq], b2L[cout]), 0.f);
                }
                atomicAdd(&poolL[cout], s);
            }
        __syncthreads();
    }

    if (tid < HID) hg[(size_t)g*HID + tid] = poolL[tid] * (1.f / NPG);
}

// ---------------------------------------------------------------------------
// MLP layer, MFMA hi/lo bf16 split, 2-way K-split, RING-3 (depth-2) prefetch.
// Block 512 thr = 8 waves (2kz x 2wm x 2wn); tile 32x64; LDS store+add merge.
// ---------------------------------------------------------------------------
template<int K, bool AF32>
__global__ __launch_bounds__(512) void k_mlp5(
    const void* __restrict__ Ahi_, const u16* __restrict__ Alo,
    const u16* __restrict__ WT, const float* __restrict__ bias,
    u16* __restrict__ Ohi, u16* __restrict__ Olo, int Nc)
{
    constexpr int ITERS = K / 64;
    __shared__ __align__(16) float red[32][68];

    const int tid = threadIdx.x;
    const int w = tid >> 6, lane = tid & 63;
    const int kz = w >> 2, wm = (w >> 1) & 1, wn = w & 1;
    const int lr = lane & 15, quad = lane >> 4;
    const int row0 = blockIdx.x * 32, col0 = blockIdx.y * 64;
    const int m = row0 + wm*16 + lr;
    const int k0 = kz * (K/2);

    const float* Af = (const float*)Ahi_;
    const u16*   Ah = (const u16*)Ahi_;

    auto loadA = [&](int it, bf16x8& hi, bf16x8& lo){
        const int kk = k0 + it*32 + quad*8;
        if constexpr (AF32){
            float xs[8];
            *(float4*)&xs[0] = *(const float4*)&Af[(size_t)m*K + kk];
            *(float4*)&xs[4] = *(const float4*)&Af[(size_t)m*K + kk + 4];
            #pragma unroll
            for (int j = 0; j < 8; j++){
                u16 hh = f2bf(xs[j]);
                hi[j] = (short)hh;
                lo[j] = (short)f2bf(xs[j] - bf2f(hh));
            }
        } else {
            hi = *(const bf16x8*)&Ah[(size_t)m*K + kk];
            lo = *(const bf16x8*)&Alo[(size_t)m*K + kk];
        }
    };
    auto loadB = [&](int it, bf16x8* b){
        const int kk = k0 + it*32 + quad*8;
        #pragma unroll
        for (int nt = 0; nt < 2; nt++){
            int n = col0 + wn*32 + nt*16 + lr;
            b[nt] = *(const bf16x8*)&WT[(size_t)n*K + kk];
        }
    };

    const f32x4 fz = {0.f, 0.f, 0.f, 0.f};
    f32x4 acc[2] = {fz, fz};
    bf16x8 hi[3], lo[3], bb[3][2];
    loadA(0, hi[0], lo[0]); loadB(0, bb[0]);
    if (ITERS > 1){ loadA(1, hi[1], lo[1]); loadB(1, bb[1]); }
    #pragma unroll
    for (int it = 0; it < ITERS; it++){
        const int sl = it % 3;
        const int pf = (it + 2) % 3;
        if (it + 2 < ITERS){ loadA(it+2, hi[pf], lo[pf]); loadB(it+2, bb[pf]); }
        #pragma unroll
        for (int nt = 0; nt < 2; nt++){
            acc[nt] = __builtin_amdgcn_mfma_f32_16x16x32_bf16(hi[sl], bb[sl][nt], acc[nt], 0, 0, 0);
            acc[nt] = __builtin_amdgcn_mfma_f32_16x16x32_bf16(lo[sl], bb[sl][nt], acc[nt], 0, 0, 0);
        }
    }

    if (kz == 1){
        #pragma unroll
        for (int nt = 0; nt < 2; nt++)
            #pragma unroll
            for (int r = 0; r < 4; r++)
                red[wm*16 + quad*4 + r][wn*32 + nt*16 + lr] = acc[nt][r];
    }
    __syncthreads();
    if (kz == 0){
        #pragma unroll
        for (int nt = 0; nt < 2; nt++)
            #pragma unroll
            for (int r = 0; r < 4; r++){
                int rr = wm*16 + quad*4 + r;
                int cc = wn*32 + nt*16 + lr;
                float v = acc[nt][r] + red[rr][cc] + bias[col0 + cc];
                v = fmaxf(v, 0.f);
                u16 hh = f2bf(v);
                size_t go = (size_t)(row0 + rr) * Nc + col0 + cc;
                Ohi[go] = hh;
                Olo[go] = f2bf(v - bf2f(hh));
            }
    }
}

// ---------------------------------------------------------------------------
// head: logits = (X4hi+X4lo) @ We + be; softmax -> out (dtype derived inline)
// ---------------------------------------------------------------------------
__global__ __launch_bounds__(64) void k_head(
    const u16* __restrict__ Xhi, const u16* __restrict__ Xlo,
    const float* __restrict__ We, const float* __restrict__ be,
    void* __restrict__ out, const u16* __restrict__ w1bits)
{
    const int g = blockIdx.x, lane = threadIdx.x;
    u16 a = w1bits[lane], b = w1bits[64 + lane];
    unsigned long long m1 = __ballot((int)((a >> 7) & 0xFF) >= 0x7F);
    unsigned long long m2 = __ballot((int)((b >> 7) & 0xFF) >= 0x7F);
    const int f = (__popcll(m1) + __popcll(m2) > 4) ? 1 : 0;

    float part[10];
    #pragma unroll
    for (int c = 0; c < 10; c++) part[c] = 0.f;
    for (int k = lane; k < 512; k += 64){
        float x = bf2f(Xhi[(size_t)g*512 + k]) + bf2f(Xlo[(size_t)g*512 + k]);
        #pragma unroll
        for (int c = 0; c < 10; c++) part[c] = fmaf(x, We[k*10 + c], part[c]);
    }
    #pragma unroll
    for (int c = 0; c < 10; c++){
        float v = part[c];
        for (int off = 32; off > 0; off >>= 1) v += __shfl_down(v, off);
        part[c] = v;
    }
    if (lane == 0){
        #pragma unroll
        for (int c = 0; c < 10; c++) part[c] += be[c];
        float m = part[0];
        #pragma unroll
        for (int c = 1; c < 10; c++) m = fmaxf(m, part[c]);
        float e[10], s = 0.f;
        #pragma unroll
        for (int c = 0; c < 10; c++){ e[c] = __expf(part[c] - m); s += e[c]; }
        float inv = 1.f / s;
        #pragma unroll
        for (int c = 0; c < 10; c++){
            float p = e[c] * inv;
            if (f) ((float*)out)[g*10 + c] = p;
            else   ((u16*)out)[g*10 + c]  = f2bf(p);
        }
    }
}

// ---------------------------------------------------------------------------
extern "C" void kernel_launch(void* const* d_in, const int* in_sizes, int n_in,
                              void* d_out, int out_size, void* d_ws, size_t ws_size,
                              hipStream_t stream)
{
    const int* src = (const int*)d_in[0];
    const int* dst = (const int*)d_in[1];

    char* ws = (char*)d_ws;
    size_t o = 0;
    float* canon    = (float*)(ws + o); o += ((size_t)cEND * 4 + 15) & ~(size_t)15;
    u16*   W2T      = (u16*)  (ws + o); o += (size_t)HID * HID * 2;
    u16*   WTa      = (u16*)  (ws + o); o += ((size_t)T_END * 2 + 15) & ~(size_t)15;
    float* hg       = (float*)(ws + o); o += (size_t)NG * HID * 4;
    u16*   X1hi     = (u16*)  (ws + o); o += (size_t)NG * 512 * 2;
    u16*   X1lo     = (u16*)  (ws + o); o += (size_t)NG * 512 * 2;
    u16*   X2hi     = (u16*)  (ws + o); o += (size_t)NG * 1024 * 2;
    u16*   X2lo     = (u16*)  (ws + o); o += (size_t)NG * 1024 * 2;
    u16*   X3hi     = (u16*)  (ws + o); o += (size_t)NG * 1024 * 2;
    u16*   X3lo     = (u16*)  (ws + o); o += (size_t)NG * 1024 * 2;
    u16*   X4hi     = (u16*)  (ws + o); o += (size_t)NG * 512 * 2;
    u16*   X4lo     = (u16*)  (ws + o); o += (size_t)NG * 512 * 2;
    (void)ws_size; (void)in_sizes; (void)n_in; (void)out_size;

    // prep: tiled transposes + canon copies
    PrepIn pin;
    for (int i = 0; i < 14; i++) pin.p[i] = d_in[2 + i];
    k_prep2<<<dim3(566), dim3(256), 0, stream>>>(pin, canon, W2T, WTa);

    const float *W1 = canon+cW1, *b1 = canon+cb1, *b2 = canon+cb2;
    const float *ba = canon+cba, *bb = canon+cbb, *bc = canon+cbc, *bd = canon+cbd;
    const float *We = canon+cWe, *be = canon+cbe;

    // mega v2: whole graph path (edges -> hg), 67KB LDS, 2 blocks/CU
    k_mega<<<dim3(NG), dim3(512), 0, stream>>>(src, dst, W1, b1, b2, W2T, hg);

    // MLP: MFMA hi/lo-split layers with ring-3 prefetch
    k_mlp5<128,  true ><<<dim3(16, 8),  dim3(512), 0, stream>>>(hg,   nullptr, WTa + T_Wa, ba, X1hi, X1lo, 512);
    k_mlp5<512,  false><<<dim3(16, 16), dim3(512), 0, stream>>>(X1hi, X1lo,    WTa + T_Wb, bb, X2hi, X2lo, 1024);
    k_mlp5<1024, false><<<dim3(16, 16), dim3(512), 0, stream>>>(X2hi, X2lo,    WTa + T_Wc, bc, X3hi, X3lo, 1024);
    k_mlp5<1024, false><<<dim3(16, 8),  dim3(512), 0, stream>>>(X3hi, X3lo,    WTa + T_Wd, bd, X4hi, X4lo, 512);

    // head + softmax
    k_head<<<dim3(NG), dim3(64), 0, stream>>>(X4hi, X4lo, We, be, d_out, (const u16*)d_in[2]);
}